// Round 16
// baseline (484.384 us; speedup 1.0000x reference)
//
#include <hip/hip_runtime.h>
#include <hip/hip_bf16.h>

typedef __attribute__((ext_vector_type(8))) short bf16x8;
typedef __attribute__((ext_vector_type(4))) unsigned short u16x4;
typedef __attribute__((ext_vector_type(4))) float f32x4;

constexpr int Bb = 4, Tt = 2048, Dd = 2048, Hh = 16, DHd = 128;

static __device__ __forceinline__ unsigned short f2bf(float f) {
  union { float f; unsigned u; } x; x.f = f;
  unsigned r = x.u + 0x7fffu + ((x.u >> 16) & 1u);
  return (unsigned short)(r >> 16);
}

// async global->LDS, 16B per lane (dest = wave-uniform base + lane*16)
static __device__ __forceinline__ void gld16(const void* g, void* l) {
  __builtin_amdgcn_global_load_lds(
      (__attribute__((address_space(1))) void*)g,
      (__attribute__((address_space(3))) void*)l, 16, 0, 0);
}

// ---------------------------------------------------------------------------
// fp32 -> bf16 bulk convert (8 elems/thread)
// ---------------------------------------------------------------------------
__global__ __launch_bounds__(256) void cvt_bf16(const float* __restrict__ s,
                                                unsigned short* __restrict__ d) {
  const size_t i = ((size_t)blockIdx.x * 256 + threadIdx.x) * 8;
  float4 a = *(const float4*)(s + i);
  float4 b = *(const float4*)(s + i + 4);
  bf16x8 pk;
  pk[0] = (short)f2bf(a.x); pk[1] = (short)f2bf(a.y);
  pk[2] = (short)f2bf(a.z); pk[3] = (short)f2bf(a.w);
  pk[4] = (short)f2bf(b.x); pk[5] = (short)f2bf(b.y);
  pk[6] = (short)f2bf(b.z); pk[7] = (short)f2bf(b.w);
  *(bf16x8*)(d + i) = pk;
}

// ---------------------------------------------------------------------------
// Weight transpose + fp32->bf16 convert: W[k][n] -> Wt[n][k]
// ---------------------------------------------------------------------------
__global__ __launch_bounds__(256) void wtrans_all(
    const float* __restrict__ Wq, const float* __restrict__ Wk,
    const float* __restrict__ Wv, const float* __restrict__ Wo,
    unsigned short* __restrict__ WqT, unsigned short* __restrict__ WkT,
    unsigned short* __restrict__ WvT, unsigned short* __restrict__ WoT,
    float qscale) {
  __shared__ __align__(16) unsigned short tile[64][72];
  const float* src;
  unsigned short* dst;
  float sc = 1.0f;
  switch (blockIdx.z) {
    case 0: src = Wq; dst = WqT; sc = qscale; break;
    case 1: src = Wk; dst = WkT; break;
    case 2: src = Wv; dst = WvT; break;
    default: src = Wo; dst = WoT; break;
  }
  const int t = threadIdx.x;
  const int k0 = blockIdx.x * 64, n0 = blockIdx.y * 64;
  const int c = t & 15, r = t >> 4;
#pragma unroll
  for (int p = 0; p < 4; ++p) {
    const int rr = r + 16 * p;
    float4 v = *(const float4*)(src + (size_t)(k0 + rr) * Dd + n0 + c * 4);
    u16x4 pk;
    pk[0] = f2bf(v.x * sc); pk[1] = f2bf(v.y * sc);
    pk[2] = f2bf(v.z * sc); pk[3] = f2bf(v.w * sc);
    *(u16x4*)&tile[rr][c * 4] = pk;
  }
  __syncthreads();
#pragma unroll
  for (int p = 0; p < 4; ++p) {
    const int nn = r + 16 * p;
    u16x4 pk;
    pk[0] = tile[c * 4 + 0][nn]; pk[1] = tile[c * 4 + 1][nn];
    pk[2] = tile[c * 4 + 2][nn]; pk[3] = tile[c * 4 + 3][nn];
    *(u16x4*)(dst + (size_t)(n0 + nn) * Dd + k0 + c * 4) = pk;
  }
}

// ---------------------------------------------------------------------------
// GEMM, r16: 2-PHASE schedule (8 -> 3 barriers/tile), full-tile prefetch
// lead preserved (r9/r14 invariant). BM=BN=256, BK=64, 8 waves (2Mx4N),
// per-wave 128x64 C (acc[8][4]). LDS: 2 bufs x 2 halves x [128][64] = 128KB.
// Per K-tile:
//  phA: read a0(8)+allB(8) | lgkmcnt(0) | bar | SB(tau+2,0/1) || 32 MFMA
//  phB: read a1(8)         | lgkmcnt(0) | bar | SA(tau+2,0/1) || 32 MFMA
//       | vmcnt(8) | bar
// Formal race-freedom: every wave's LDS reads of a region retire to regs
// (lgkmcnt(0)) BEFORE the barrier after which any wave issues the DMA that
// overwrites it. vmcnt(8): outstanding = B(t+1)+A(t+1)+B(t+2)+A(t+2)=16,
// retires exactly tile tau+1 (full-tile lead -> HBM latency covered).
// LDS chunk-XOR swizzle (chunk ^= row&7) on source+read. XCD-swizzled grid.
// OMODE: 0 = fp32 flat [M][N]; 1 = bf16 [B,H,T,dh]; 2 = bf16 [B,H,dh,T]
// ---------------------------------------------------------------------------
template <int OMODE>
__global__ __launch_bounds__(512, 2) void gemm8p(
    const unsigned short* __restrict__ A, const unsigned short* __restrict__ Bt,
    void* __restrict__ Outp) {
  __shared__ __align__(16) unsigned short As[2][2][128 * 64];
  __shared__ __align__(16) unsigned short Bs[2][2][128 * 64];
  const int t = threadIdx.x, lane = t & 63, w = t >> 6;
  const int wm = w >> 2, wn = w & 3;
  const int fr = lane & 15, fq = lane >> 4;
  const int sw = fr & 7;
  const int slot = blockIdx.x;
  const int orig = (slot & 7) * 32 + (slot >> 3);
  const int m0 = (orig >> 3) * 256, n0 = (orig & 7) * 256;

  const int srow = t >> 3, sch = t & 7;
  const int scol = (sch ^ (srow & 7)) * 8;  // pre-swizzled source chunk

  auto SA = [&](int tau, int h) {
    const unsigned short* g =
        A + (size_t)(m0 + h * 128 + srow) * Dd + tau * 64 + scol;
    unsigned short* l = &As[tau & 1][h][(srow * 8 + sch) * 8];
    gld16(g, l);
    gld16(g + (size_t)64 * Dd, l + 4096);
  };
  auto SB = [&](int tau, int h) {
    const unsigned short* g =
        Bt + (size_t)(n0 + h * 128 + srow) * Dd + tau * 64 + scol;
    unsigned short* l = &Bs[tau & 1][h][(srow * 8 + sch) * 8];
    gld16(g, l);
    gld16(g + (size_t)64 * Dd, l + 4096);
  };

  f32x4 acc[8][4] = {};
  constexpr int NT = Dd / 64;  // 32

  SB(0, 0); SB(0, 1); SA(0, 0); SA(0, 1);
  SB(1, 0); SB(1, 1); SA(1, 0); SA(1, 1);
  asm volatile("s_waitcnt vmcnt(8)" ::: "memory");
  __builtin_amdgcn_s_barrier();
  __builtin_amdgcn_sched_barrier(0);

  for (int tau = 0; tau < NT; ++tau) {
    const unsigned short* Ab = &As[tau & 1][wm][0];
    const unsigned short* Bb = &Bs[tau & 1][wn >> 1][0];
    const int brow = (wn & 1) * 64;

    bf16x8 a0[4][2], a1[4][2], bl[4][2];

    // ---------------- phase A: quadrants (m0-3, n0-3)
#pragma unroll
    for (int i = 0; i < 4; ++i)
#pragma unroll
      for (int ks = 0; ks < 2; ++ks)
        a0[i][ks] = *(const bf16x8*)&Ab[(i * 16 + fr) * 64 +
                                        (((ks * 4 + fq) ^ sw)) * 8];
#pragma unroll
    for (int j = 0; j < 4; ++j)
#pragma unroll
      for (int ks = 0; ks < 2; ++ks)
        bl[j][ks] = *(const bf16x8*)&Bb[(brow + j * 16 + fr) * 64 +
                                        (((ks * 4 + fq) ^ sw)) * 8];
    asm volatile("s_waitcnt lgkmcnt(0)" ::: "memory");  // reads in regs
    __builtin_amdgcn_sched_barrier(0);
    __builtin_amdgcn_s_barrier();  // all waves' B reads retired
    __builtin_amdgcn_sched_barrier(0);
    if (tau + 2 < NT) {  // B-region of buf[tau&1] now recyclable
      SB(tau + 2, 0);
      SB(tau + 2, 1);
    }
    __builtin_amdgcn_s_setprio(1);
#pragma unroll
    for (int i = 0; i < 4; ++i)
#pragma unroll
      for (int j = 0; j < 4; ++j)
#pragma unroll
        for (int ks = 0; ks < 2; ++ks)
          acc[i][j] = __builtin_amdgcn_mfma_f32_16x16x32_bf16(
              a0[i][ks], bl[j][ks], acc[i][j], 0, 0, 0);
    __builtin_amdgcn_s_setprio(0);
    __builtin_amdgcn_sched_barrier(0);

    // ---------------- phase B: quadrants (m4-7, n0-3)
#pragma unroll
    for (int i = 0; i < 4; ++i)
#pragma unroll
      for (int ks = 0; ks < 2; ++ks)
        a1[i][ks] = *(const bf16x8*)&Ab[((i + 4) * 16 + fr) * 64 +
                                        (((ks * 4 + fq) ^ sw)) * 8];
    asm volatile("s_waitcnt lgkmcnt(0)" ::: "memory");  // a1 in regs
    __builtin_amdgcn_sched_barrier(0);
    __builtin_amdgcn_s_barrier();  // all waves' A reads (a0+a1) retired
    __builtin_amdgcn_sched_barrier(0);
    if (tau + 2 < NT) {  // A-region of buf[tau&1] now recyclable
      SA(tau + 2, 0);
      SA(tau + 2, 1);
    }
    __builtin_amdgcn_s_setprio(1);
#pragma unroll
    for (int i = 0; i < 4; ++i)
#pragma unroll
      for (int j = 0; j < 4; ++j)
#pragma unroll
        for (int ks = 0; ks < 2; ++ks)
          acc[i + 4][j] = __builtin_amdgcn_mfma_f32_16x16x32_bf16(
              a1[i][ks], bl[j][ks], acc[i + 4][j], 0, 0, 0);
    __builtin_amdgcn_s_setprio(0);
    __builtin_amdgcn_sched_barrier(0);
    if (tau + 2 < NT) {
      asm volatile("s_waitcnt vmcnt(8)" ::: "memory");  // tile tau+1 landed
    } else if (tau + 1 < NT) {
      asm volatile("s_waitcnt vmcnt(0)" ::: "memory");  // tail drain
    }
    __builtin_amdgcn_s_barrier();  // next iter reads buf[(tau+1)&1]
    __builtin_amdgcn_sched_barrier(0);
  }

#pragma unroll
  for (int m = 0; m < 8; ++m) {
    const int mg = m0 + wm * 128 + m * 16 + fq * 4;
    const int bb = mg >> 11, tt0 = mg & (Tt - 1);
#pragma unroll
    for (int n = 0; n < 4; ++n) {
      const int ng = n0 + wn * 64 + n * 16 + fr;
      if (OMODE == 0) {
        float* o = (float*)Outp + (size_t)mg * Dd + ng;
#pragma unroll
        for (int r = 0; r < 4; ++r) o[(size_t)r * Dd] = acc[m][n][r];
      } else if (OMODE == 1) {
        const int h = ng >> 7, dh = ng & 127;
        unsigned short* o = (unsigned short*)Outp +
                            (((size_t)bb * Hh + h) * Tt + tt0) * DHd + dh;
#pragma unroll
        for (int r = 0; r < 4; ++r) o[r * DHd] = f2bf(acc[m][n][r]);
      } else {
        const int h = ng >> 7, dh = ng & 127;
        u16x4 pk;
#pragma unroll
        for (int r = 0; r < 4; ++r) pk[r] = f2bf(acc[m][n][r]);
        *(u16x4*)((unsigned short*)Outp +
                  (((size_t)bb * Hh + h) * DHd + dh) * Tt + tt0) = pk;
      }
    }
  }
}

// ---------------------------------------------------------------------------
// Causal flash attention (r13 state, proven). QBLK=256 (8 waves x 32 q-rows),
// KVBLK=64, 2 blocks/CU = 16 waves/CU, complementary qb pairing per XCD.
// Single barrier per tile (wait-one-behind); K/V XOR-swizzled; S^T=mfma(K,Q)
// per-lane scalar softmax, exp2 domain, defer-max, in-reg shfl P redist.
// ---------------------------------------------------------------------------
__global__ __launch_bounds__(512, 2) void fattn(
    const unsigned short* __restrict__ Qp, const unsigned short* __restrict__ Kp,
    const unsigned short* __restrict__ Vt, unsigned short* __restrict__ Ao) {
  __shared__ __align__(16) unsigned short Ks[2][64 * 128];
  __shared__ __align__(16) unsigned short Vs[2][128 * 64];
  const int t = threadIdx.x, lane = t & 63, w = t >> 6;
  const int fr = lane & 15, fq = lane >> 4;
  const int rsw = fr & 7;
  const int id = blockIdx.x;
  const int xcd = id & 7, slot = id >> 3;
  const int s5 = slot >> 5, r_ = slot & 31;
  const int bh = xcd * 8 + (r_ >> 2);
  const int q2 = r_ & 3;
  const int qb = s5 ? q2 : 7 - q2;
  const int q0w = qb * 256 + w * 32;
  const unsigned short* Qb = Qp + (size_t)bh * Tt * DHd;
  const unsigned short* Kb = Kp + (size_t)bh * Tt * DHd;
  const unsigned short* Vb = Vt + (size_t)bh * DHd * Tt;

  bf16x8 qf[2][4];
#pragma unroll
  for (int mg = 0; mg < 2; ++mg)
#pragma unroll
    for (int ks = 0; ks < 4; ++ks)
      qf[mg][ks] = *(const bf16x8*)(Qb + (size_t)(q0w + mg * 16 + fr) * DHd +
                                    ks * 32 + fq * 8);

  f32x4 oacc[2][8] = {};
  float m_[2] = {-1e30f, -1e30f};
  float l_[2] = {0.f, 0.f};

  auto STAGE = [&](int b, int kv0) {
#pragma unroll
    for (int p = 0; p < 2; ++p) {
      const int idx = t + p * 512, row = idx >> 4, ch = idx & 15;
      gld16(Kb + (size_t)(kv0 + row) * DHd + ((ch ^ (row & 7)) * 8),
            &Ks[b][idx * 8]);
    }
#pragma unroll
    for (int p = 0; p < 2; ++p) {
      const int idx = t + p * 512, row = idx >> 3, ch = idx & 7;
      gld16(Vb + (size_t)row * Tt + kv0 + ((ch ^ (row & 7)) * 8),
            &Vs[b][idx * 8]);
    }
  };

  const int ntile = 4 * qb + 4;
  STAGE(0, 0);
  asm volatile("s_waitcnt vmcnt(0)" ::: "memory");  // tile 0 landed (own loads)
  int cur = 0;

  for (int kt = 0; kt < ntile; ++kt) {
    const int kv0 = kt * 64;
    __builtin_amdgcn_s_barrier();
    if (kt + 1 < ntile) STAGE(cur ^ 1, (kt + 1) * 64);
    __builtin_amdgcn_sched_barrier(0);

    if (kv0 <= q0w + 31) {
      const unsigned short* Kc = &Ks[cur][0];
      const unsigned short* Vc = &Vs[cur][0];

      f32x4 s[2][4] = {};
      __builtin_amdgcn_s_setprio(1);
#pragma unroll
      for (int tt = 0; tt < 4; ++tt) {
        bf16x8 kf[4];
#pragma unroll
        for (int ks = 0; ks < 4; ++ks)
          kf[ks] = *(const bf16x8*)(Kc + (tt * 16 + fr) * 128 +
                                    ((ks * 4 + fq) ^ rsw) * 8);
#pragma unroll
        for (int ks = 0; ks < 4; ++ks) {
          s[0][tt] = __builtin_amdgcn_mfma_f32_16x16x32_bf16(kf[ks], qf[0][ks],
                                                             s[0][tt], 0, 0, 0);
          s[1][tt] = __builtin_amdgcn_mfma_f32_16x16x32_bf16(kf[ks], qf[1][ks],
                                                             s[1][tt], 0, 0, 0);
        }
      }
      __builtin_amdgcn_s_setprio(0);

      uint2 c[2][4];
#pragma unroll
      for (int mg = 0; mg < 2; ++mg) {
        const int qg = q0w + mg * 16;
        if (kv0 + 63 > qg) {
          const int qa = qg + fr;
#pragma unroll
          for (int tt = 0; tt < 4; ++tt)
#pragma unroll
            for (int r = 0; r < 4; ++r)
              if (kv0 + tt * 16 + fq * 4 + r > qa) s[mg][tt][r] = -1e30f;
        }

        float tmax = s[mg][0][0];
#pragma unroll
        for (int tt = 0; tt < 4; ++tt)
#pragma unroll
          for (int r = 0; r < 4; ++r) tmax = fmaxf(tmax, s[mg][tt][r]);
        tmax = fmaxf(tmax, __shfl_xor(tmax, 16));
        tmax = fmaxf(tmax, __shfl_xor(tmax, 32));

        if (!__all(tmax <= m_[mg] + 8.0f)) {
          const float mn = fmaxf(m_[mg], tmax);
          const float alpha = __builtin_amdgcn_exp2f(m_[mg] - mn);
          m_[mg] = mn;
          float al4[4];
#pragma unroll
          for (int r = 0; r < 4; ++r) al4[r] = __shfl(alpha, fq * 4 + r);
#pragma unroll
          for (int dt = 0; dt < 8; ++dt)
#pragma unroll
            for (int r = 0; r < 4; ++r) oacc[mg][dt][r] *= al4[r];
          l_[mg] *= alpha;
        }

        float rs = 0.f;
#pragma unroll
        for (int tt = 0; tt < 4; ++tt)
#pragma unroll
          for (int r = 0; r < 4; ++r) {
            const float p = __builtin_amdgcn_exp2f(s[mg][tt][r] - m_[mg]);
            s[mg][tt][r] = p;
            rs += p;
          }
        rs += __shfl_xor(rs, 16);
        rs += __shfl_xor(rs, 32);
        l_[mg] += rs;

#pragma unroll
        for (int tt = 0; tt < 4; ++tt) {
          unsigned r0, r1;
          asm("v_cvt_pk_bf16_f32 %0, %1, %2"
              : "=v"(r0) : "v"(s[mg][tt][0]), "v"(s[mg][tt][1]));
          asm("v_cvt_pk_bf16_f32 %0, %1, %2"
              : "=v"(r1) : "v"(s[mg][tt][2]), "v"(s[mg][tt][3]));
          c[mg][tt].x = r0; c[mg][tt].y = r1;
        }
      }

      const int src0 = fr + 32 * (fq & 1);
      const int src1 = src0 + 16;
      const bool hi = (fq >> 1) != 0;
      __builtin_amdgcn_s_setprio(1);
#pragma unroll
      for (int ks2 = 0; ks2 < 2; ++ks2) {
        bf16x8 pf[2];
#pragma unroll
        for (int mg = 0; mg < 2; ++mg) {
          const int a0 = __shfl((int)c[mg][2 * ks2].x, src0);
          const int b0 = __shfl((int)c[mg][2 * ks2 + 1].x, src0);
          const int a1 = __shfl((int)c[mg][2 * ks2].y, src0);
          const int b1 = __shfl((int)c[mg][2 * ks2 + 1].y, src0);
          const int a2 = __shfl((int)c[mg][2 * ks2].x, src1);
          const int b2 = __shfl((int)c[mg][2 * ks2 + 1].x, src1);
          const int a3 = __shfl((int)c[mg][2 * ks2].y, src1);
          const int b3 = __shfl((int)c[mg][2 * ks2 + 1].y, src1);
          union { int wd[4]; bf16x8 v; } pu;
          pu.wd[0] = hi ? b0 : a0;
          pu.wd[1] = hi ? b1 : a1;
          pu.wd[2] = hi ? b2 : a2;
          pu.wd[3] = hi ? b3 : a3;
          pf[mg] = pu.v;
        }
#pragma unroll
        for (int dt = 0; dt < 8; ++dt) {
          const bf16x8 vf = *(const bf16x8*)(Vc + (dt * 16 + fr) * 64 +
                                             ((ks2 * 4 + fq) ^ rsw) * 8);
          oacc[0][dt] = __builtin_amdgcn_mfma_f32_16x16x32_bf16(pf[0], vf,
                                                                oacc[0][dt], 0, 0, 0);
          oacc[1][dt] = __builtin_amdgcn_mfma_f32_16x16x32_bf16(pf[1], vf,
                                                                oacc[1][dt], 0, 0, 0);
        }
      }
      __builtin_amdgcn_s_setprio(0);
    }

    if (kt + 1 < ntile)
      asm volatile("s_waitcnt vmcnt(0)" ::: "memory");
    cur ^= 1;
  }

  const int bb = bh >> 4, hh = bh & 15;
#pragma unroll
  for (int mg = 0; mg < 2; ++mg) {
    float linv[4];
#pragma unroll
    for (int r = 0; r < 4; ++r) linv[r] = 1.0f / __shfl(l_[mg], fq * 4 + r);
    const int qrow = q0w + mg * 16 + fq * 4;
#pragma unroll
    for (int r = 0; r < 4; ++r) {
      unsigned short* o = Ao + ((size_t)bb * Tt + qrow + r) * Dd + hh * DHd + fr;
#pragma unroll
      for (int dt = 0; dt < 8; ++dt) o[dt * 16] = f2bf(oacc[mg][dt][r] * linv[r]);
    }
  }
}

// ---------------------------------------------------------------------------
extern "C" void kernel_launch(void* const* d_in, const int* in_sizes, int n_in,
                              void* d_out, int out_size, void* d_ws, size_t ws_size,
                              hipStream_t stream) {
  const float* q = (const float*)d_in[0];
  const float* k = (const float*)d_in[1];
  const float* v = (const float*)d_in[2];
  // d_in[3] = mask (known causal tril; unused)
  const float* Wq = (const float*)d_in[4];
  const float* Wk = (const float*)d_in[5];
  const float* Wv = (const float*)d_in[6];
  const float* Wo = (const float*)d_in[7];

  const size_t WE = (size_t)Dd * Dd;
  const size_t PE = (size_t)Bb * Hh * Tt * DHd;
  unsigned short* WqT = (unsigned short*)d_ws;
  unsigned short* WkT = WqT + WE;
  unsigned short* WvT = WkT + WE;
  unsigned short* WoT = WvT + WE;
  unsigned short* Qx = WoT + WE;  // [B,H,T,dh]
  unsigned short* Kx = Qx + PE;   // [B,H,T,dh]
  unsigned short* Vx = Kx + PE;   // [B,H,dh,T]
  unsigned short* Ax = Vx + PE;   // bf16 staging, then attn out [B,T,H*dh]

  // scores in exp2 domain: fold log2(e)/sqrt(dk) into Wq
  const float qscale = (float)(1.4426950408889634 / 11.313708498984761);
  wtrans_all<<<dim3(32, 32, 4), 256, 0, stream>>>(
      Wq, Wk, Wv, Wo, WqT, WkT, WvT, WoT, qscale);

  cvt_bf16<<<dim3(8192), 256, 0, stream>>>(q, Ax);
  gemm8p<1><<<dim3(256), 512, 0, stream>>>(Ax, WqT, Qx);
  cvt_bf16<<<dim3(8192), 256, 0, stream>>>(k, Ax);
  gemm8p<1><<<dim3(256), 512, 0, stream>>>(Ax, WkT, Kx);
  cvt_bf16<<<dim3(8192), 256, 0, stream>>>(v, Ax);
  gemm8p<2><<<dim3(256), 512, 0, stream>>>(Ax, WvT, Vx);
  fattn<<<dim3(512), 512, 0, stream>>>(Qx, Kx, Vx, Ax);
  gemm8p<0><<<dim3(256), 512, 0, stream>>>(Ax, WoT, (float*)d_out);
}

// Round 17
// 477.987 us; speedup vs baseline: 1.0134x; 1.0134x over previous
//
#include <hip/hip_runtime.h>
#include <hip/hip_bf16.h>

typedef __attribute__((ext_vector_type(8))) short bf16x8;
typedef __attribute__((ext_vector_type(4))) unsigned short u16x4;
typedef __attribute__((ext_vector_type(4))) float f32x4;

constexpr int Bb = 4, Tt = 2048, Dd = 2048, Hh = 16, DHd = 128;

static __device__ __forceinline__ unsigned short f2bf(float f) {
  union { float f; unsigned u; } x; x.f = f;
  unsigned r = x.u + 0x7fffu + ((x.u >> 16) & 1u);
  return (unsigned short)(r >> 16);
}

// async global->LDS, 16B per lane (dest = wave-uniform base + lane*16)
static __device__ __forceinline__ void gld16(const void* g, void* l) {
  __builtin_amdgcn_global_load_lds(
      (__attribute__((address_space(1))) void*)g,
      (__attribute__((address_space(3))) void*)l, 16, 0, 0);
}

// ---------------------------------------------------------------------------
// fp32 -> bf16 bulk convert (8 elems/thread)
// ---------------------------------------------------------------------------
__global__ __launch_bounds__(256) void cvt_bf16(const float* __restrict__ s,
                                                unsigned short* __restrict__ d) {
  const size_t i = ((size_t)blockIdx.x * 256 + threadIdx.x) * 8;
  float4 a = *(const float4*)(s + i);
  float4 b = *(const float4*)(s + i + 4);
  bf16x8 pk;
  pk[0] = (short)f2bf(a.x); pk[1] = (short)f2bf(a.y);
  pk[2] = (short)f2bf(a.z); pk[3] = (short)f2bf(a.w);
  pk[4] = (short)f2bf(b.x); pk[5] = (short)f2bf(b.y);
  pk[6] = (short)f2bf(b.z); pk[7] = (short)f2bf(b.w);
  *(bf16x8*)(d + i) = pk;
}

// ---------------------------------------------------------------------------
// Weight transpose + fp32->bf16 convert: W[k][n] -> Wt[n][k]
// ---------------------------------------------------------------------------
__global__ __launch_bounds__(256) void wtrans_all(
    const float* __restrict__ Wq, const float* __restrict__ Wk,
    const float* __restrict__ Wv, const float* __restrict__ Wo,
    unsigned short* __restrict__ WqT, unsigned short* __restrict__ WkT,
    unsigned short* __restrict__ WvT, unsigned short* __restrict__ WoT,
    float qscale) {
  __shared__ __align__(16) unsigned short tile[64][72];
  const float* src;
  unsigned short* dst;
  float sc = 1.0f;
  switch (blockIdx.z) {
    case 0: src = Wq; dst = WqT; sc = qscale; break;
    case 1: src = Wk; dst = WkT; break;
    case 2: src = Wv; dst = WvT; break;
    default: src = Wo; dst = WoT; break;
  }
  const int t = threadIdx.x;
  const int k0 = blockIdx.x * 64, n0 = blockIdx.y * 64;
  const int c = t & 15, r = t >> 4;
#pragma unroll
  for (int p = 0; p < 4; ++p) {
    const int rr = r + 16 * p;
    float4 v = *(const float4*)(src + (size_t)(k0 + rr) * Dd + n0 + c * 4);
    u16x4 pk;
    pk[0] = f2bf(v.x * sc); pk[1] = f2bf(v.y * sc);
    pk[2] = f2bf(v.z * sc); pk[3] = f2bf(v.w * sc);
    *(u16x4*)&tile[rr][c * 4] = pk;
  }
  __syncthreads();
#pragma unroll
  for (int p = 0; p < 4; ++p) {
    const int nn = r + 16 * p;
    u16x4 pk;
    pk[0] = tile[c * 4 + 0][nn]; pk[1] = tile[c * 4 + 1][nn];
    pk[2] = tile[c * 4 + 2][nn]; pk[3] = tile[c * 4 + 3][nn];
    *(u16x4*)(dst + (size_t)(n0 + nn) * Dd + k0 + c * 4) = pk;
  }
}

// ---------------------------------------------------------------------------
// GEMM, m201-style 8-phase schedule (r9 champion: full-tile prefetch lead).
// BM=BN=256, BK=64, 8 waves (2Mx4N), per-wave 128x64 C (acc[8][4]).
// LDS: 2 bufs x 2 halves x [128][64] for A,B = 128 KB. Per K-tile: 4 phases,
// one C-quadrant (16 MFMA) each; ALL of tile tau+2's staging in iteration
// tau via region recycling (SB @ph2, SA @ph3); vmcnt(8) at ph3 retires
// exactly tile tau+1's 8 loads (issued a FULL TILE earlier -> HBM latency
// covered). Schedule-shape probes (r14 spread, r16 2-phase) both regressed:
// this bunched full-lead 4-phase form is the measured optimum.
// LDS chunk-XOR swizzle (chunk ^= row&7) on source+read. XCD-swizzled grid.
// OMODE: 0 = fp32 flat [M][N]; 1 = bf16 [B,H,T,dh]; 2 = bf16 [B,H,dh,T]
// ---------------------------------------------------------------------------
template <int OMODE>
__global__ __launch_bounds__(512, 2) void gemm8p(
    const unsigned short* __restrict__ A, const unsigned short* __restrict__ Bt,
    void* __restrict__ Outp) {
  __shared__ __align__(16) unsigned short As[2][2][128 * 64];
  __shared__ __align__(16) unsigned short Bs[2][2][128 * 64];
  const int t = threadIdx.x, lane = t & 63, w = t >> 6;
  const int wm = w >> 2, wn = w & 3;
  const int fr = lane & 15, fq = lane >> 4;
  const int sw = fr & 7;
  const int slot = blockIdx.x;
  const int orig = (slot & 7) * 32 + (slot >> 3);
  const int m0 = (orig >> 3) * 256, n0 = (orig & 7) * 256;

  const int srow = t >> 3, sch = t & 7;
  const int scol = (sch ^ (srow & 7)) * 8;  // pre-swizzled source chunk

  auto SA = [&](int tau, int h) {
    const unsigned short* g =
        A + (size_t)(m0 + h * 128 + srow) * Dd + tau * 64 + scol;
    unsigned short* l = &As[tau & 1][h][(srow * 8 + sch) * 8];
    gld16(g, l);
    gld16(g + (size_t)64 * Dd, l + 4096);
  };
  auto SB = [&](int tau, int h) {
    const unsigned short* g =
        Bt + (size_t)(n0 + h * 128 + srow) * Dd + tau * 64 + scol;
    unsigned short* l = &Bs[tau & 1][h][(srow * 8 + sch) * 8];
    gld16(g, l);
    gld16(g + (size_t)64 * Dd, l + 4096);
  };

  f32x4 acc[8][4] = {};
  constexpr int NT = Dd / 64;  // 32

  SB(0, 0); SB(0, 1); SA(0, 0); SA(0, 1);
  SB(1, 0); SB(1, 1); SA(1, 0); SA(1, 1);
  asm volatile("s_waitcnt vmcnt(8)" ::: "memory");
  __builtin_amdgcn_s_barrier();
  __builtin_amdgcn_sched_barrier(0);

  for (int tau = 0; tau < NT; ++tau) {
    const unsigned short* Ab = &As[tau & 1][wm][0];
    const unsigned short* Bb = &Bs[tau & 1][wn >> 1][0];
    const int brow = (wn & 1) * 64;

    bf16x8 a0[4][2], a1[4][2], b0[2][2], b1[2][2];

    // ---------------- phase 0: quadrant (m0-3, n0-1)
#pragma unroll
    for (int i = 0; i < 4; ++i)
#pragma unroll
      for (int ks = 0; ks < 2; ++ks)
        a0[i][ks] = *(const bf16x8*)&Ab[(i * 16 + fr) * 64 +
                                        (((ks * 4 + fq) ^ sw)) * 8];
#pragma unroll
    for (int j = 0; j < 2; ++j)
#pragma unroll
      for (int ks = 0; ks < 2; ++ks)
        b0[j][ks] = *(const bf16x8*)&Bb[(brow + j * 16 + fr) * 64 +
                                        (((ks * 4 + fq) ^ sw)) * 8];
    __builtin_amdgcn_s_barrier();
    __builtin_amdgcn_sched_barrier(0);
    __builtin_amdgcn_s_setprio(1);
#pragma unroll
    for (int i = 0; i < 4; ++i)
#pragma unroll
      for (int j = 0; j < 2; ++j)
#pragma unroll
        for (int ks = 0; ks < 2; ++ks)
          acc[i][j] = __builtin_amdgcn_mfma_f32_16x16x32_bf16(
              a0[i][ks], b0[j][ks], acc[i][j], 0, 0, 0);
    __builtin_amdgcn_s_setprio(0);
    __builtin_amdgcn_sched_barrier(0);
    __builtin_amdgcn_s_barrier();

    // ---------------- phase 1: quadrant (m0-3, n2-3)
#pragma unroll
    for (int j = 0; j < 2; ++j)
#pragma unroll
      for (int ks = 0; ks < 2; ++ks)
        b1[j][ks] = *(const bf16x8*)&Bb[(brow + (j + 2) * 16 + fr) * 64 +
                                        (((ks * 4 + fq) ^ sw)) * 8];
    __builtin_amdgcn_s_barrier();
    __builtin_amdgcn_sched_barrier(0);
    __builtin_amdgcn_s_setprio(1);
#pragma unroll
    for (int i = 0; i < 4; ++i)
#pragma unroll
      for (int j = 0; j < 2; ++j)
#pragma unroll
        for (int ks = 0; ks < 2; ++ks)
          acc[i][j + 2] = __builtin_amdgcn_mfma_f32_16x16x32_bf16(
              a0[i][ks], b1[j][ks], acc[i][j + 2], 0, 0, 0);
    __builtin_amdgcn_s_setprio(0);
    __builtin_amdgcn_sched_barrier(0);
    __builtin_amdgcn_s_barrier();

    // ---------------- phase 2: quadrant (m4-7, n0-1)
#pragma unroll
    for (int i = 0; i < 4; ++i)
#pragma unroll
      for (int ks = 0; ks < 2; ++ks)
        a1[i][ks] = *(const bf16x8*)&Ab[((i + 4) * 16 + fr) * 64 +
                                        (((ks * 4 + fq) ^ sw)) * 8];
    if (tau + 2 < NT) {  // B-region of buf[tau&1] consumed by ph1's barrier
      SB(tau + 2, 0);
      SB(tau + 2, 1);
    }
    __builtin_amdgcn_s_barrier();
    __builtin_amdgcn_sched_barrier(0);
    __builtin_amdgcn_s_setprio(1);
#pragma unroll
    for (int i = 0; i < 4; ++i)
#pragma unroll
      for (int j = 0; j < 2; ++j)
#pragma unroll
        for (int ks = 0; ks < 2; ++ks)
          acc[i + 4][j] = __builtin_amdgcn_mfma_f32_16x16x32_bf16(
              a1[i][ks], b0[j][ks], acc[i + 4][j], 0, 0, 0);
    __builtin_amdgcn_s_setprio(0);
    __builtin_amdgcn_sched_barrier(0);
    __builtin_amdgcn_s_barrier();

    // ---------------- phase 3: quadrant (m4-7, n2-3)
    if (tau + 2 < NT) {  // A-region of buf[tau&1] consumed by ph2's barrier
      SA(tau + 2, 0);
      SA(tau + 2, 1);
      asm volatile("s_waitcnt vmcnt(8)" ::: "memory");  // tile tau+1 landed
    } else {
      asm volatile("s_waitcnt vmcnt(0)" ::: "memory");  // tail drain
    }
    __builtin_amdgcn_s_barrier();
    __builtin_amdgcn_sched_barrier(0);
    __builtin_amdgcn_s_setprio(1);
#pragma unroll
    for (int i = 0; i < 4; ++i)
#pragma unroll
      for (int j = 0; j < 2; ++j)
#pragma unroll
        for (int ks = 0; ks < 2; ++ks)
          acc[i + 4][j + 2] = __builtin_amdgcn_mfma_f32_16x16x32_bf16(
              a1[i][ks], b1[j][ks], acc[i + 4][j + 2], 0, 0, 0);
    __builtin_amdgcn_s_setprio(0);
    __builtin_amdgcn_sched_barrier(0);
    __builtin_amdgcn_s_barrier();
  }

#pragma unroll
  for (int m = 0; m < 8; ++m) {
    const int mg = m0 + wm * 128 + m * 16 + fq * 4;
    const int bb = mg >> 11, tt0 = mg & (Tt - 1);
#pragma unroll
    for (int n = 0; n < 4; ++n) {
      const int ng = n0 + wn * 64 + n * 16 + fr;
      if (OMODE == 0) {
        float* o = (float*)Outp + (size_t)mg * Dd + ng;
#pragma unroll
        for (int r = 0; r < 4; ++r) o[(size_t)r * Dd] = acc[m][n][r];
      } else if (OMODE == 1) {
        const int h = ng >> 7, dh = ng & 127;
        unsigned short* o = (unsigned short*)Outp +
                            (((size_t)bb * Hh + h) * Tt + tt0) * DHd + dh;
#pragma unroll
        for (int r = 0; r < 4; ++r) o[r * DHd] = f2bf(acc[m][n][r]);
      } else {
        const int h = ng >> 7, dh = ng & 127;
        u16x4 pk;
#pragma unroll
        for (int r = 0; r < 4; ++r) pk[r] = f2bf(acc[m][n][r]);
        *(u16x4*)((unsigned short*)Outp +
                  (((size_t)bb * Hh + h) * DHd + dh) * Tt + tt0) = pk;
      }
    }
  }
}

// ---------------------------------------------------------------------------
// Causal flash attention (r13 state, proven). QBLK=256 (8 waves x 32 q-rows),
// KVBLK=64, 2 blocks/CU = 16 waves/CU, complementary qb pairing per XCD.
// Single barrier per tile (wait-one-behind); K/V XOR-swizzled; S^T=mfma(K,Q)
// per-lane scalar softmax, exp2 domain, defer-max, in-reg shfl P redist.
// ---------------------------------------------------------------------------
__global__ __launch_bounds__(512, 2) void fattn(
    const unsigned short* __restrict__ Qp, const unsigned short* __restrict__ Kp,
    const unsigned short* __restrict__ Vt, unsigned short* __restrict__ Ao) {
  __shared__ __align__(16) unsigned short Ks[2][64 * 128];
  __shared__ __align__(16) unsigned short Vs[2][128 * 64];
  const int t = threadIdx.x, lane = t & 63, w = t >> 6;
  const int fr = lane & 15, fq = lane >> 4;
  const int rsw = fr & 7;
  const int id = blockIdx.x;
  const int xcd = id & 7, slot = id >> 3;
  const int s5 = slot >> 5, r_ = slot & 31;
  const int bh = xcd * 8 + (r_ >> 2);
  const int q2 = r_ & 3;
  const int qb = s5 ? q2 : 7 - q2;
  const int q0w = qb * 256 + w * 32;
  const unsigned short* Qb = Qp + (size_t)bh * Tt * DHd;
  const unsigned short* Kb = Kp + (size_t)bh * Tt * DHd;
  const unsigned short* Vb = Vt + (size_t)bh * DHd * Tt;

  bf16x8 qf[2][4];
#pragma unroll
  for (int mg = 0; mg < 2; ++mg)
#pragma unroll
    for (int ks = 0; ks < 4; ++ks)
      qf[mg][ks] = *(const bf16x8*)(Qb + (size_t)(q0w + mg * 16 + fr) * DHd +
                                    ks * 32 + fq * 8);

  f32x4 oacc[2][8] = {};
  float m_[2] = {-1e30f, -1e30f};
  float l_[2] = {0.f, 0.f};

  auto STAGE = [&](int b, int kv0) {
#pragma unroll
    for (int p = 0; p < 2; ++p) {
      const int idx = t + p * 512, row = idx >> 4, ch = idx & 15;
      gld16(Kb + (size_t)(kv0 + row) * DHd + ((ch ^ (row & 7)) * 8),
            &Ks[b][idx * 8]);
    }
#pragma unroll
    for (int p = 0; p < 2; ++p) {
      const int idx = t + p * 512, row = idx >> 3, ch = idx & 7;
      gld16(Vb + (size_t)row * Tt + kv0 + ((ch ^ (row & 7)) * 8),
            &Vs[b][idx * 8]);
    }
  };

  const int ntile = 4 * qb + 4;
  STAGE(0, 0);
  asm volatile("s_waitcnt vmcnt(0)" ::: "memory");  // tile 0 landed (own loads)
  int cur = 0;

  for (int kt = 0; kt < ntile; ++kt) {
    const int kv0 = kt * 64;
    __builtin_amdgcn_s_barrier();
    if (kt + 1 < ntile) STAGE(cur ^ 1, (kt + 1) * 64);
    __builtin_amdgcn_sched_barrier(0);

    if (kv0 <= q0w + 31) {
      const unsigned short* Kc = &Ks[cur][0];
      const unsigned short* Vc = &Vs[cur][0];

      f32x4 s[2][4] = {};
      __builtin_amdgcn_s_setprio(1);
#pragma unroll
      for (int tt = 0; tt < 4; ++tt) {
        bf16x8 kf[4];
#pragma unroll
        for (int ks = 0; ks < 4; ++ks)
          kf[ks] = *(const bf16x8*)(Kc + (tt * 16 + fr) * 128 +
                                    ((ks * 4 + fq) ^ rsw) * 8);
#pragma unroll
        for (int ks = 0; ks < 4; ++ks) {
          s[0][tt] = __builtin_amdgcn_mfma_f32_16x16x32_bf16(kf[ks], qf[0][ks],
                                                             s[0][tt], 0, 0, 0);
          s[1][tt] = __builtin_amdgcn_mfma_f32_16x16x32_bf16(kf[ks], qf[1][ks],
                                                             s[1][tt], 0, 0, 0);
        }
      }
      __builtin_amdgcn_s_setprio(0);

      uint2 c[2][4];
#pragma unroll
      for (int mg = 0; mg < 2; ++mg) {
        const int qg = q0w + mg * 16;
        if (kv0 + 63 > qg) {
          const int qa = qg + fr;
#pragma unroll
          for (int tt = 0; tt < 4; ++tt)
#pragma unroll
            for (int r = 0; r < 4; ++r)
              if (kv0 + tt * 16 + fq * 4 + r > qa) s[mg][tt][r] = -1e30f;
        }

        float tmax = s[mg][0][0];
#pragma unroll
        for (int tt = 0; tt < 4; ++tt)
#pragma unroll
          for (int r = 0; r < 4; ++r) tmax = fmaxf(tmax, s[mg][tt][r]);
        tmax = fmaxf(tmax, __shfl_xor(tmax, 16));
        tmax = fmaxf(tmax, __shfl_xor(tmax, 32));

        if (!__all(tmax <= m_[mg] + 8.0f)) {
          const float mn = fmaxf(m_[mg], tmax);
          const float alpha = __builtin_amdgcn_exp2f(m_[mg] - mn);
          m_[mg] = mn;
          float al4[4];
#pragma unroll
          for (int r = 0; r < 4; ++r) al4[r] = __shfl(alpha, fq * 4 + r);
#pragma unroll
          for (int dt = 0; dt < 8; ++dt)
#pragma unroll
            for (int r = 0; r < 4; ++r) oacc[mg][dt][r] *= al4[r];
          l_[mg] *= alpha;
        }

        float rs = 0.f;
#pragma unroll
        for (int tt = 0; tt < 4; ++tt)
#pragma unroll
          for (int r = 0; r < 4; ++r) {
            const float p = __builtin_amdgcn_exp2f(s[mg][tt][r] - m_[mg]);
            s[mg][tt][r] = p;
            rs += p;
          }
        rs += __shfl_xor(rs, 16);
        rs += __shfl_xor(rs, 32);
        l_[mg] += rs;

#pragma unroll
        for (int tt = 0; tt < 4; ++tt) {
          unsigned r0, r1;
          asm("v_cvt_pk_bf16_f32 %0, %1, %2"
              : "=v"(r0) : "v"(s[mg][tt][0]), "v"(s[mg][tt][1]));
          asm("v_cvt_pk_bf16_f32 %0, %1, %2"
              : "=v"(r1) : "v"(s[mg][tt][2]), "v"(s[mg][tt][3]));
          c[mg][tt].x = r0; c[mg][tt].y = r1;
        }
      }

      const int src0 = fr + 32 * (fq & 1);
      const int src1 = src0 + 16;
      const bool hi = (fq >> 1) != 0;
      __builtin_amdgcn_s_setprio(1);
#pragma unroll
      for (int ks2 = 0; ks2 < 2; ++ks2) {
        bf16x8 pf[2];
#pragma unroll
        for (int mg = 0; mg < 2; ++mg) {
          const int a0 = __shfl((int)c[mg][2 * ks2].x, src0);
          const int b0 = __shfl((int)c[mg][2 * ks2 + 1].x, src0);
          const int a1 = __shfl((int)c[mg][2 * ks2].y, src0);
          const int b1 = __shfl((int)c[mg][2 * ks2 + 1].y, src0);
          const int a2 = __shfl((int)c[mg][2 * ks2].x, src1);
          const int b2 = __shfl((int)c[mg][2 * ks2 + 1].x, src1);
          const int a3 = __shfl((int)c[mg][2 * ks2].y, src1);
          const int b3 = __shfl((int)c[mg][2 * ks2 + 1].y, src1);
          union { int wd[4]; bf16x8 v; } pu;
          pu.wd[0] = hi ? b0 : a0;
          pu.wd[1] = hi ? b1 : a1;
          pu.wd[2] = hi ? b2 : a2;
          pu.wd[3] = hi ? b3 : a3;
          pf[mg] = pu.v;
        }
#pragma unroll
        for (int dt = 0; dt < 8; ++dt) {
          const bf16x8 vf = *(const bf16x8*)(Vc + (dt * 16 + fr) * 64 +
                                             ((ks2 * 4 + fq) ^ rsw) * 8);
          oacc[0][dt] = __builtin_amdgcn_mfma_f32_16x16x32_bf16(pf[0], vf,
                                                                oacc[0][dt], 0, 0, 0);
          oacc[1][dt] = __builtin_amdgcn_mfma_f32_16x16x32_bf16(pf[1], vf,
                                                                oacc[1][dt], 0, 0, 0);
        }
      }
      __builtin_amdgcn_s_setprio(0);
    }

    if (kt + 1 < ntile)
      asm volatile("s_waitcnt vmcnt(0)" ::: "memory");
    cur ^= 1;
  }

  const int bb = bh >> 4, hh = bh & 15;
#pragma unroll
  for (int mg = 0; mg < 2; ++mg) {
    float linv[4];
#pragma unroll
    for (int r = 0; r < 4; ++r) linv[r] = 1.0f / __shfl(l_[mg], fq * 4 + r);
    const int qrow = q0w + mg * 16 + fq * 4;
#pragma unroll
    for (int r = 0; r < 4; ++r) {
      unsigned short* o = Ao + ((size_t)bb * Tt + qrow + r) * Dd + hh * DHd + fr;
#pragma unroll
      for (int dt = 0; dt < 8; ++dt) o[dt * 16] = f2bf(oacc[mg][dt][r] * linv[r]);
    }
  }
}

// ---------------------------------------------------------------------------
extern "C" void kernel_launch(void* const* d_in, const int* in_sizes, int n_in,
                              void* d_out, int out_size, void* d_ws, size_t ws_size,
                              hipStream_t stream) {
  const float* q = (const float*)d_in[0];
  const float* k = (const float*)d_in[1];
  const float* v = (const float*)d_in[2];
  // d_in[3] = mask (known causal tril; unused)
  const float* Wq = (const float*)d_in[4];
  const float* Wk = (const float*)d_in[5];
  const float* Wv = (const float*)d_in[6];
  const float* Wo = (const float*)d_in[7];

  const size_t WE = (size_t)Dd * Dd;
  const size_t PE = (size_t)Bb * Hh * Tt * DHd;
  unsigned short* WqT = (unsigned short*)d_ws;
  unsigned short* WkT = WqT + WE;
  unsigned short* WvT = WkT + WE;
  unsigned short* WoT = WvT + WE;
  unsigned short* Qx = WoT + WE;  // [B,H,T,dh]
  unsigned short* Kx = Qx + PE;   // [B,H,T,dh]
  unsigned short* Vx = Kx + PE;   // [B,H,dh,T]
  unsigned short* Ax = Vx + PE;   // bf16 staging, then attn out [B,T,H*dh]

  // scores in exp2 domain: fold log2(e)/sqrt(dk) into Wq
  const float qscale = (float)(1.4426950408889634 / 11.313708498984761);
  wtrans_all<<<dim3(32, 32, 4), 256, 0, stream>>>(
      Wq, Wk, Wv, Wo, WqT, WkT, WvT, WoT, qscale);

  cvt_bf16<<<dim3(8192), 256, 0, stream>>>(q, Ax);
  gemm8p<1><<<dim3(256), 512, 0, stream>>>(Ax, WqT, Qx);
  cvt_bf16<<<dim3(8192), 256, 0, stream>>>(k, Ax);
  gemm8p<1><<<dim3(256), 512, 0, stream>>>(Ax, WkT, Kx);
  cvt_bf16<<<dim3(8192), 256, 0, stream>>>(v, Ax);
  gemm8p<2><<<dim3(256), 512, 0, stream>>>(Ax, WvT, Vx);
  fattn<<<dim3(512), 512, 0, stream>>>(Qx, Kx, Vx, Ax);
  gemm8p<0><<<dim3(256), 512, 0, stream>>>(Ax, WoT, (float*)d_out);
}